// Round 8
// baseline (272.844 us; speedup 1.0000x reference)
//
#include <hip/hip_runtime.h>
#include <cmath>

namespace {
constexpr int BN = 1024;
constexpr int NC = 96;
constexpr int MT = 256;
constexpr int UL = 40;
constexpr int LS = 81;     // 2*UL+1 states
constexpr int PAIRS = 41;  // pairs per row (lane i -> states 2i, 2i+1)
constexpr int PST = 258;   // LDS prob-row stride in shorts (bank-friendly)

template <int CTRL>
__device__ __forceinline__ float dppf(float v) {
  return __builtin_bit_cast(
      float, __builtin_amdgcn_update_dpp(0, __builtin_bit_cast(int, v), CTRL,
                                         0xf, 0xf, true));
}
__device__ __forceinline__ float rl63(float x) {
  return __builtin_bit_cast(
      float, __builtin_amdgcn_readlane(__builtin_bit_cast(int, x), 63));
}
__device__ __forceinline__ float wave_sum(float x) {
  x += dppf<0x111>(x);
  x += dppf<0x112>(x);
  x += dppf<0x114>(x);
  x += dppf<0x118>(x);
  x += dppf<0x142>(x);
  x += dppf<0x143>(x);
  return rl63(x);
}
// lane i <- lane i-1 (lane 0 <- 0)
__device__ __forceinline__ float wave_shr1(float v) { return dppf<0x138>(v); }
__device__ __forceinline__ float fast_rcp(float x) {
  return __builtin_amdgcn_rcpf(x);
}
__device__ __forceinline__ unsigned short f2bf(float x) {
  return (unsigned short)(__builtin_bit_cast(unsigned, x) >> 16);  // truncate
}
__device__ __forceinline__ float bf2f(unsigned short h) {
  return __builtin_bit_cast(float, (unsigned)h << 16);
}
__device__ __forceinline__ ushort2 pack2(float a, float b) {
  ushort2 r; r.x = f2bf(a); r.y = f2bf(b); return r;
}

constexpr float FQ = 1e8f;      // nominal row scale (shock headroom)
constexpr float SEPS = 1e-30f;  // rcp-input floor (NaN-proof)

// One wave per (item, phase). Lane i owns states s=2i, 2i+1. Chains run
// UNNORMALIZED with deadbeat compensated rescale (row scale = product of the
// last three step multipliers exactly; FIR, shock-immune). Alpha stores
// x = u*r = a_raw/p (division-free); beta stores raw rows REVERSED. All prob
// reads come from LDS (staged bf16) -> the K-loop has NO global loads.
__global__ __launch_bounds__(64) void chain_kernel(
    const float* __restrict__ gout, const int* __restrict__ glabel,
    const int* __restrict__ gw, ushort2* __restrict__ a_st,
    ushort2* __restrict__ b_st, float* __restrict__ sums_a,
    float* __restrict__ sums_b) {
  __shared__ unsigned short pl[41 * PST];  // rows 0..39 label, 40 blank
  const int bx = blockIdx.x;
  const int b = bx >> 1, ph = bx & 1;
  const int i = threadIdx.x;
  const float* P = gout + (size_t)b * (NC * MT);  // P[c*MT + t]
  const int* lab = glabel + b * UL;
  const int T = gw[b] >> 2;  // [128,256]

  // ---- stage probs to LDS (coalesced float4 per row; full 256 t) ----
  for (int j = 0; j < 41; ++j) {
    int cj;
    if (ph == 0) cj = (j < 40) ? lab[j] : 0;
    else cj = (j < 40) ? (NC - 1 - lab[39 - j]) : (NC - 1);
    float4 v = reinterpret_cast<const float4*>(P + (size_t)cj * MT)[i];
    ushort2* dst = reinterpret_cast<ushort2*>(&pl[j * PST + 4 * i]);
    dst[0] = pack2(v.x, v.y);
    dst[1] = pack2(v.z, v.w);
  }
  __syncthreads();

  const int s0 = 2 * i, s1 = s0 + 1;
  const float h0f = (i <= 40) ? 1.f : 0.f;
  const float h1f = (i <= 39) ? 1.f : 0.f;
  const int iw = (i <= 40) ? i : 40;
  const int iw2 = (i <= 39) ? i : 39;  // label LDS row for this lane

  float mskf;
  ushort2* rows;
  float* sums;
  if (ph == 0) {
    const int li = (i < UL) ? lab[i] : 0;
    const int lm = (i >= 1 && i < UL) ? lab[i - 1] : 0;
    mskf = (i >= 1 && i <= 39 && li != lm) ? 1.f : 0.f;
    rows = a_st + (size_t)b * MT * PAIRS;
    sums = sums_a + (size_t)b * MT;
  } else {
    const int rli = (i < UL) ? lab[UL - 1 - i] : 0;
    const int rlm = (i >= 1 && i < UL) ? lab[UL - i] : 0;
    mskf = (i >= 1 && i <= 39 && rli != rlm) ? 1.f : 0.f;
    rows = b_st + (size_t)b * MT * PAIRS;
    sums = sums_b + (size_t)b * MT;
  }
  const unsigned short* lrow = &pl[iw2 * PST];  // label probs, this lane
  const unsigned short* brow = &pl[40 * PST];   // blank probs (uniform)

  // t = 0
  float v0 = (i == 0) ? bf2f(brow[0]) : 0.f;
  float v1 = (i == 0) ? bf2f(lrow[0]) : 0.f;
  float ss = wave_sum(v0 + v1);
  if (i == 0) sums[0] = ss;
  float r0q = FQ * fast_rcp(fmaxf(ss, SEPS));
  float r1q = FQ * fast_rcp(fmaxf(ss * r0q, SEPS));
  float r2q = FQ * fast_rcp(fmaxf(ss * r0q * r1q, SEPS));

  ushort2* wa = rows + iw;         // alpha: row t, pair i
  ushort2* wb = rows + (40 - iw);  // beta: row t-1 (delayed), rev pair
  if (ph == 0) {
    if (i <= 40) *wa = pack2((i == 0) ? 1.f : 0.f, (i == 0) ? 1.f : 0.f);
    wa += PAIRS;
  }

  // depth-2 LDS prefetch (ds_read ~120cyc << 2 steps)
  float pbq0 = bf2f(brow[1]), plq0 = bf2f(lrow[1]);
  float pbq1 = bf2f(brow[2]), plq1 = bf2f(lrow[2]);
#pragma unroll 2
  for (int t = 1; t < T; ++t) {
    float pm1 = wave_shr1(v1);  // prev row, state 2i-1
    if (ph == 1) {              // store prev beta row reversed
      if (i <= 40) *wb = pack2(v0, pm1);
      wb += PAIRS;
    }
    const float rh0 = r0q * h0f, rh1 = r0q * h1f;
    float u0 = v0 + pm1;
    float u1 = (v0 + v1) + pm1 * mskf;
    const int start = LS - 2 * (T - t);
    if (s0 < start) u0 = 0.f;
    if (s1 < start) u1 = 0.f;
    const float x0 = u0 * rh0, x1 = u1 * rh1;  // = n/p exactly
    float n0 = x0 * pbq0;
    float n1 = x1 * plq0;
    if (ph == 0) {
      if (i <= 40) *wa = pack2(x0, x1);
      wa += PAIRS;
    }
    v0 = n0; v1 = n1;
    float ssn = wave_sum(n0 + n1);  // 3-step slack to consumer rn
    if (i == 0) sums[t] = ssn;
    float rn = FQ * fast_rcp(fmaxf(ssn, SEPS) * r1q * r2q);
    rn = fminf(fmaxf(rn, 1e-20f), 1e20f);  // close inf->NaN feedback loop
    r0q = r1q; r1q = r2q; r2q = rn;
    int tn = t + 2; if (tn > 255) tn = 255;  // LDS holds all 256 t
    pbq0 = pbq1; plq0 = plq1;
    pbq1 = bf2f(brow[tn]); plq1 = bf2f(lrow[tn]);
  }
  if (ph == 1) {  // final beta row T-1
    float pm1f = wave_shr1(v1);
    if (i <= 40) *wb = pack2(v0, pm1f);
  }
}

// Fully parallel combine: block = item, 8 waves; wave w handles t = w, w+8...
// lh_t = sum_s x[t][s]*brev[T-1-t][s] / (sa_t * sb_{T-1-t}).
__global__ __launch_bounds__(512) void combine_kernel(
    const int* __restrict__ gw, const ushort2* __restrict__ a_st,
    const ushort2* __restrict__ b_st, const float* __restrict__ sums_a,
    const float* __restrict__ sums_b, float* __restrict__ loss_out) {
  const int b = blockIdx.x;
  const int w = threadIdx.x >> 6;
  const int i = threadIdx.x & 63;
  const int T = gw[b] >> 2;
  const ushort2* A = a_st + (size_t)b * MT * PAIRS;
  const ushort2* Bs = b_st + (size_t)b * MT * PAIRS;
  const float* sa = sums_a + (size_t)b * MT;
  const float* sb = sums_b + (size_t)b * MT;
  const int iw = (i <= 40) ? i : 40;
  const float hv = (i <= 40) ? 1.f : 0.f;

  float lsum = 0.f;
  int t = w;
  if (t < T) {
    ushort2 ap = A[(size_t)t * PAIRS + iw];
    ushort2 bp = Bs[(size_t)(T - 1 - t) * PAIRS + iw];
    float sav = sa[t], sbv = sb[T - 1 - t];
    while (true) {
      const int t2 = t + 8;
      const bool more = (t2 < T);
      const int tc = more ? t2 : t;
      ushort2 ap2 = A[(size_t)tc * PAIRS + iw];
      ushort2 bp2 = Bs[(size_t)(T - 1 - tc) * PAIRS + iw];
      float sav2 = sa[tc], sbv2 = sb[T - 1 - tc];
      float d = (bf2f(ap.x) * bf2f(bp.x) + bf2f(ap.y) * bf2f(bp.y)) * hv;
      d = wave_sum(d);
      float lh = d * fast_rcp(fmaxf(sav, SEPS)) * fast_rcp(fmaxf(sbv, SEPS));
      lsum -= __logf(fmaxf(lh, 1e-37f));
      if (!more) break;
      ap = ap2; bp = bp2; sav = sav2; sbv = sbv2; t = t2;
    }
  }
  __shared__ float part[8];
  if (i == 0) part[w] = lsum;
  __syncthreads();
  if (threadIdx.x == 0) {
    float L = 0.f;
#pragma unroll
    for (int k = 0; k < 8; ++k) L += part[k];
    loss_out[b] = fminf(fmaxf(L, -1e30f), 1e30f);  // fmin/fmax absorb NaN
  }
}

__global__ void reduce_kernel(const float* __restrict__ loss_in,
                              float* __restrict__ out) {
  __shared__ double sm[256];
  const int tid = threadIdx.x;
  double s = 0.0;
  for (int k = tid; k < BN; k += 256) s += (double)loss_in[k];
  sm[tid] = s;
  __syncthreads();
  for (int w = 128; w >= 1; w >>= 1) {
    if (tid < w) sm[tid] += sm[tid + w];
    __syncthreads();
  }
  if (tid == 0) out[0] = (float)sm[0];
}
}  // namespace

extern "C" void kernel_launch(void* const* d_in, const int* in_sizes, int n_in,
                              void* d_out, int out_size, void* d_ws, size_t ws_size,
                              hipStream_t stream) {
  const float* gout = (const float*)d_in[0];
  const int* glabel = (const int*)d_in[1];
  const int* gw = (const int*)d_in[2];
  ushort2* a_st = (ushort2*)d_ws;                  // 1024*256*41 pairs (43 MB)
  ushort2* b_st = a_st + (size_t)BN * MT * PAIRS;  // 43 MB
  float* sums_a = (float*)(b_st + (size_t)BN * MT * PAIRS);  // 1 MB
  float* sums_b = sums_a + (size_t)BN * MT;                  // 1 MB
  float* loss = sums_b + (size_t)BN * MT;                    // 4 KB
  chain_kernel<<<2 * BN, 64, 0, stream>>>(gout, glabel, gw, a_st, b_st,
                                          sums_a, sums_b);
  combine_kernel<<<BN, 512, 0, stream>>>(gw, a_st, b_st, sums_a, sums_b, loss);
  reduce_kernel<<<1, 256, 0, stream>>>(loss, (float*)d_out);
}

// Round 9
// 200.168 us; speedup vs baseline: 1.3631x; 1.3631x over previous
//
#include <hip/hip_runtime.h>
#include <cmath>

namespace {
constexpr int BN = 1024;
constexpr int NC = 96;
constexpr int MT = 256;
constexpr int UL = 40;
constexpr int LS = 81;     // 2*UL+1 states
constexpr int PAIRS = 41;  // pairs per row (lane i -> states 2i, 2i+1)

template <int CTRL>
__device__ __forceinline__ float dppf(float v) {
  return __builtin_bit_cast(
      float, __builtin_amdgcn_update_dpp(0, __builtin_bit_cast(int, v), CTRL,
                                         0xf, 0xf, true));
}
__device__ __forceinline__ float rl63(float x) {
  return __builtin_bit_cast(
      float, __builtin_amdgcn_readlane(__builtin_bit_cast(int, x), 63));
}
__device__ __forceinline__ float wave_sum(float x) {
  x += dppf<0x111>(x);
  x += dppf<0x112>(x);
  x += dppf<0x114>(x);
  x += dppf<0x118>(x);
  x += dppf<0x142>(x);
  x += dppf<0x143>(x);
  return rl63(x);
}
// lane i <- lane i-1 (lane 0 <- 0)
__device__ __forceinline__ float wave_shr1(float v) { return dppf<0x138>(v); }
__device__ __forceinline__ float fast_rcp(float x) {
  return __builtin_amdgcn_rcpf(x);
}
__device__ __forceinline__ unsigned packu(float a, float b) {
  unsigned ua = __builtin_bit_cast(unsigned, a) >> 16;
  unsigned ub = __builtin_bit_cast(unsigned, b) & 0xffff0000u;
  return ua | ub;
}
__device__ __forceinline__ float bf_lo(unsigned u) {
  return __builtin_bit_cast(float, u << 16);
}
__device__ __forceinline__ float bf_hi(unsigned u) {
  return __builtin_bit_cast(float, u & 0xffff0000u);
}

constexpr float FQ = 1e8f;      // nominal row scale (shock headroom)
constexpr float SEPS = 1e-30f;  // rcp-input floor (NaN-proof)

// One wave per (item, phase). Lane i owns states s=2i, 2i+1. Chains run
// UNNORMALIZED with deadbeat compensated rescale (row scale = product of the
// last three step multipliers exactly; FIR, shock-immune). Rows are
// normalized by their own raw sum AT STORE TIME (x' = (a/p)/ss, b' = raw/ss)
// so no sums arrays are needed. Outputs stored TRANSPOSED [pair][t] (bf16x2)
// with 8-step register bursts -> 2 dwordx4 stores / 8 steps; probs prefetched
// 8 steps ahead as float4 pairs. Beta rows stored pair-reversed so slot j of
// chain row r equals reference b[T-1-r][states 2j,2j+1].
__global__ __launch_bounds__(64) void chain_kernel(
    const float* __restrict__ gout, const int* __restrict__ glabel,
    const int* __restrict__ gw, unsigned* __restrict__ xa,
    unsigned* __restrict__ xb) {
  const int bx = blockIdx.x;
  const int b = bx >> 1, ph = bx & 1;
  const int i = threadIdx.x;
  const float* P = gout + (size_t)b * (NC * MT);  // P[c*MT + t]
  const int* lab = glabel + b * UL;
  const int T = gw[b] >> 2;  // [128,256]

  const int s0 = 2 * i, s1 = s0 + 1;
  const float h0f = (i <= 40) ? 1.f : 0.f;
  const float h1f = (i <= 39) ? 1.f : 0.f;
  const int iw = (i <= 40) ? i : 40;
  const bool act = (i <= 40);

  const float* pB;
  const float* pL;
  float mskf;
  unsigned* outp;
  if (ph == 0) {  // alpha
    const int li = (i < UL) ? lab[i] : 0;
    const int lm = (i >= 1 && i < UL) ? lab[i - 1] : 0;
    pB = P;
    pL = P + (size_t)li * MT;
    mskf = (i >= 1 && i <= 39 && li != lm) ? 1.f : 0.f;
    outp = xa + ((size_t)b * PAIRS + iw) * MT;
  } else {  // beta: class-flipped probs, reversed labels
    const int rli = (i < UL) ? lab[UL - 1 - i] : 0;
    const int rlm = (i >= 1 && i < UL) ? lab[UL - i] : 0;
    pB = P + (size_t)(NC - 1) * MT;
    pL = P + (size_t)(NC - 1 - rli) * MT;
    mskf = (i >= 1 && i <= 39 && rli != rlm) ? 1.f : 0.f;
    outp = xb + ((size_t)b * PAIRS + (40 - iw)) * MT;  // pair-reversed column
  }

  // ---- prob pipeline: current block unpacked, next block in flight ----
  float pbv[8], plv[8];
  float4 LA = *(const float4*)(pB + 0), LB = *(const float4*)(pB + 4);
  float4 MA = *(const float4*)(pL + 0), MB = *(const float4*)(pL + 4);
  pbv[0] = LA.x; pbv[1] = LA.y; pbv[2] = LA.z; pbv[3] = LA.w;
  pbv[4] = LB.x; pbv[5] = LB.y; pbv[6] = LB.z; pbv[7] = LB.w;
  plv[0] = MA.x; plv[1] = MA.y; plv[2] = MA.z; plv[3] = MA.w;
  plv[4] = MB.x; plv[5] = MB.y; plv[6] = MB.z; plv[7] = MB.w;
  LA = *(const float4*)(pB + 8); LB = *(const float4*)(pB + 12);
  MA = *(const float4*)(pL + 8); MB = *(const float4*)(pL + 12);

  // ---- t = 0 ----
  float v0 = (i == 0) ? pbv[0] : 0.f;
  float v1 = (i == 0) ? plv[0] : 0.f;
  float ss = wave_sum(v0 + v1);
  float r0q = FQ * fast_rcp(fmaxf(ss, SEPS));
  float r1q = FQ * fast_rcp(fmaxf(ss * r0q, SEPS));
  float r2q = FQ * fast_rcp(fmaxf(ss * r0q * r1q, SEPS));

  float f0[8], f1[8], fs[8];  // 8-step row buffer + row sums
  fs[0] = ss;
  if (ph == 0) {
    f0[0] = (i == 0) ? 1.f : 0.f;  // x = a_raw/p at t=0
    f1[0] = f0[0];
  } else {
    f0[0] = v0;
    f1[0] = 0.f;  // overwritten by step k=1's pm1
  }

#define CTC_STEP(T_, K_)                                              \
  {                                                                   \
    float pm1 = wave_shr1(v1);                                        \
    if (ph == 1 && (K_) >= 1) f1[(K_)-1] = pm1;                       \
    const float rh0 = r0q * h0f, rh1 = r0q * h1f;                     \
    float u0 = v0 + pm1;                                              \
    float u1 = (v0 + v1) + pm1 * mskf;                                \
    const int start_ = LS - 2 * (T - (T_));                           \
    if (s0 < start_) u0 = 0.f;                                        \
    if (s1 < start_) u1 = 0.f;                                        \
    const float x0 = u0 * rh0, x1 = u1 * rh1;                         \
    float n0 = x0 * pbv[(K_)];                                        \
    float n1 = x1 * plv[(K_)];                                        \
    float ssn = wave_sum(n0 + n1);                                    \
    float rn = FQ * fast_rcp(fmaxf(ssn, SEPS) * r1q * r2q);           \
    rn = fminf(fmaxf(rn, 1e-20f), 1e20f);                             \
    r0q = r1q; r1q = r2q; r2q = rn;                                   \
    v0 = n0; v1 = n1;                                                 \
    fs[(K_)] = ssn;                                                   \
    if (ph == 0) { f0[(K_)] = x0; f1[(K_)] = x1; }                    \
    else { f0[(K_)] = n0; }                                           \
  }

#define CTC_BURST(T0_)                                                \
  {                                                                   \
    if (ph == 1) f1[7] = wave_shr1(v1);                               \
    if (act) {                                                        \
      unsigned ob[8];                                                 \
      _Pragma("unroll")                                               \
      for (int k = 0; k < 8; ++k) {                                   \
        float inv = fast_rcp(fmaxf(fs[k], SEPS));                     \
        ob[k] = packu(f0[k] * inv, f1[k] * inv);                      \
      }                                                               \
      if ((T0_) + 7 < T) {                                            \
        *reinterpret_cast<uint4*>(outp + (T0_)) =                     \
            make_uint4(ob[0], ob[1], ob[2], ob[3]);                   \
        *reinterpret_cast<uint4*>(outp + (T0_) + 4) =                 \
            make_uint4(ob[4], ob[5], ob[6], ob[7]);                   \
      } else {                                                        \
        _Pragma("unroll")                                             \
        for (int k = 0; k < 8; ++k)                                   \
          if ((T0_) + k < T) outp[(T0_) + k] = ob[k];                 \
      }                                                               \
    }                                                                 \
  }

  // ---- prologue: steps 1..7, rows 0..7 ----
#pragma unroll
  for (int k = 1; k < 8; ++k) CTC_STEP(k, k);
  CTC_BURST(0);

  // ---- main: blocks of 8 steps ----
  for (int t0 = 8; t0 < T; t0 += 8) {
    pbv[0] = LA.x; pbv[1] = LA.y; pbv[2] = LA.z; pbv[3] = LA.w;
    pbv[4] = LB.x; pbv[5] = LB.y; pbv[6] = LB.z; pbv[7] = LB.w;
    plv[0] = MA.x; plv[1] = MA.y; plv[2] = MA.z; plv[3] = MA.w;
    plv[4] = MB.x; plv[5] = MB.y; plv[6] = MB.z; plv[7] = MB.w;
    int np = t0 + 8;
    if (np > 248) np = 248;
    LA = *(const float4*)(pB + np); LB = *(const float4*)(pB + np + 4);
    MA = *(const float4*)(pL + np); MB = *(const float4*)(pL + np + 4);
#pragma unroll
    for (int k = 0; k < 8; ++k) CTC_STEP(t0 + k, k);
    CTC_BURST(t0);
  }
#undef CTC_STEP
#undef CTC_BURST
}

// Fully parallel combine: block = item, thread = t. All loads coalesced
// (transposed layout). lh_t = sum_p x'[p][t] * b'[p][T-1-t]; no sums needed
// (rows pre-normalized at store).
__global__ __launch_bounds__(256) void combine_kernel(
    const int* __restrict__ gw, const unsigned* __restrict__ xa,
    const unsigned* __restrict__ xb, float* __restrict__ loss_out) {
  const int b = blockIdx.x;
  const int tid = threadIdx.x;
  const int T = gw[b] >> 2;
  float lsum = 0.f;
  if (tid < T) {
    const unsigned* A = xa + (size_t)b * PAIRS * MT + tid;
    const unsigned* Bb = xb + (size_t)b * PAIRS * MT + (T - 1 - tid);
    float d = 0.f;
#pragma unroll
    for (int p = 0; p < PAIRS; ++p) {
      const unsigned av = A[p * MT];
      const unsigned bv = Bb[p * MT];
      d = fmaf(bf_lo(av), bf_lo(bv), d);
      d = fmaf(bf_hi(av), bf_hi(bv), d);
    }
    lsum = -__logf(fmaxf(d, 1e-37f));
  }
  lsum = wave_sum(lsum);
  __shared__ float part[4];
  if ((tid & 63) == 0) part[tid >> 6] = lsum;
  __syncthreads();
  if (tid == 0) {
    float L = part[0] + part[1] + part[2] + part[3];
    loss_out[b] = fminf(fmaxf(L, -1e30f), 1e30f);  // fmin/fmax absorb NaN
  }
}

__global__ void reduce_kernel(const float* __restrict__ loss_in,
                              float* __restrict__ out) {
  __shared__ double sm[256];
  const int tid = threadIdx.x;
  double s = 0.0;
  for (int k = tid; k < BN; k += 256) s += (double)loss_in[k];
  sm[tid] = s;
  __syncthreads();
  for (int w = 128; w >= 1; w >>= 1) {
    if (tid < w) sm[tid] += sm[tid + w];
    __syncthreads();
  }
  if (tid == 0) out[0] = (float)sm[0];
}
}  // namespace

extern "C" void kernel_launch(void* const* d_in, const int* in_sizes, int n_in,
                              void* d_out, int out_size, void* d_ws, size_t ws_size,
                              hipStream_t stream) {
  const float* gout = (const float*)d_in[0];
  const int* glabel = (const int*)d_in[1];
  const int* gw = (const int*)d_in[2];
  unsigned* xa = (unsigned*)d_ws;                  // BN*PAIRS*MT uints (43 MB)
  unsigned* xb = xa + (size_t)BN * PAIRS * MT;     // 43 MB
  float* loss = (float*)(xb + (size_t)BN * PAIRS * MT);  // 4 KB
  chain_kernel<<<2 * BN, 64, 0, stream>>>(gout, glabel, gw, xa, xb);
  combine_kernel<<<BN, 256, 0, stream>>>(gw, xa, xb, loss);
  reduce_kernel<<<1, 256, 0, stream>>>(loss, (float*)d_out);
}